// Round 11
// baseline (88.738 us; speedup 1.0000x reference)
//
#include <hip/hip_runtime.h>

// AdaPT_Linear: per-tensor int8 quantized linear.
// out = (qx @ qw^T).f32 / (sa*sw) + qb.f32/sb
// x: [16384,1024] f32, w: [1024,1024] f32, b: [1024] f32, out: [16384,1024] f32

#define M_ROWS 16384
#define K_DIM  1024
#define N_OUT  1024

typedef int v4i __attribute__((ext_vector_type(4)));
typedef float v4f __attribute__((ext_vector_type(4)));

__device__ __forceinline__ float block_reduce_max4(float m, float* red) {
#pragma unroll
  for (int off = 32; off > 0; off >>= 1)
    m = fmaxf(m, __shfl_down(m, off));
  const int wid = threadIdx.x >> 6, lane = threadIdx.x & 63;
  if (lane == 0) red[wid] = m;
  __syncthreads();
  float r = fmaxf(fmaxf(red[0], red[1]), fmaxf(red[2], red[3]));
  __syncthreads();
  return r;
}

// fused: blocks [0,2048) reduce x -> px, blocks [2048,2304) reduce w -> pw
__global__ void amax_both(const float* __restrict__ x, const float* __restrict__ wsrc,
                          float* __restrict__ px, float* __restrict__ pw) {
  __shared__ float red[4];
  const bool isx = blockIdx.x < 2048;
  const float* src = isx ? x : wsrc;
  const int n4   = isx ? (M_ROWS * K_DIM / 4) : (N_OUT * K_DIM / 4);
  const int nblk = isx ? 2048 : 256;
  const int bidl = isx ? blockIdx.x : blockIdx.x - 2048;
  float m = 0.0f;
  const int stride = nblk * 256;
  for (int idx = bidl * 256 + threadIdx.x; idx < n4; idx += stride) {
    float4 v = ((const float4*)src)[idx];
    m = fmaxf(m, fmaxf(fmaxf(fabsf(v.x), fabsf(v.y)), fmaxf(fabsf(v.z), fabsf(v.w))));
  }
  float r = block_reduce_max4(m, red);
  if (threadIdx.x == 0) (isx ? px : pw)[bidl] = r;
}

__global__ void finalize_kernel(const float* __restrict__ px, int npx,
                                const float* __restrict__ pw, int npw,
                                const float* __restrict__ bias,
                                float* __restrict__ amax,
                                float* __restrict__ bdeq) {
  __shared__ float red[4];
  const int tid = threadIdx.x;

  float m = 0.0f;
  for (int i = tid; i < npx; i += 256) m = fmaxf(m, px[i]);
  float rx = block_reduce_max4(m, red);

  m = 0.0f;
  for (int i = tid; i < npw; i += 256) m = fmaxf(m, pw[i]);
  float rw = block_reduce_max4(m, red);

  float4 bv = ((const float4*)bias)[tid];  // 256*4 == 1024 exactly
  m = fmaxf(fmaxf(fabsf(bv.x), fabsf(bv.y)), fmaxf(fabsf(bv.z), fabsf(bv.w)));
  float rb = block_reduce_max4(m, red);

  if (rx == 0.0f) rx = 1.0f;
  if (rw == 0.0f) rw = 1.0f;
  if (rb == 0.0f) rb = 1.0f;
  if (tid == 0) {
    amax[0] = rx;
    amax[1] = rw;
    amax[2] = rb;
  }
  const float sb = 127.0f / rb;
  float4 q;
  q.x = fminf(fmaxf(rintf(sb * bv.x), -127.0f), 127.0f) / sb;
  q.y = fminf(fmaxf(rintf(sb * bv.y), -127.0f), 127.0f) / sb;
  q.z = fminf(fmaxf(rintf(sb * bv.z), -127.0f), 127.0f) / sb;
  q.w = fminf(fmaxf(rintf(sb * bv.w), -127.0f), 127.0f) / sb;
  ((float4*)bdeq)[tid] = q;
}

// fused: blocks [0,2048) quantize x -> qx (slot 0), [2048,2304) w -> qw (slot 1)
__global__ void quant_both(const float* __restrict__ x, const float* __restrict__ wsrc,
                           signed char* __restrict__ qx, signed char* __restrict__ qw,
                           const float* __restrict__ amax) {
  const bool isx = blockIdx.x < 2048;
  const float* src = isx ? x : wsrc;
  signed char* dst = isx ? qx : qw;
  const int n4   = isx ? (M_ROWS * K_DIM / 4) : (N_OUT * K_DIM / 4);
  const int nblk = isx ? 2048 : 256;
  const int bidl = isx ? blockIdx.x : blockIdx.x - 2048;
  const float s = 127.0f / amax[isx ? 0 : 1];
  const int stride = nblk * 256;
  for (int idx = bidl * 256 + threadIdx.x; idx < n4; idx += stride) {
    float4 v = ((const float4*)src)[idx];
    int q0 = (int)fminf(fmaxf(rintf(s * v.x), -127.0f), 127.0f);
    int q1 = (int)fminf(fmaxf(rintf(s * v.y), -127.0f), 127.0f);
    int q2 = (int)fminf(fmaxf(rintf(s * v.z), -127.0f), 127.0f);
    int q3 = (int)fminf(fmaxf(rintf(s * v.w), -127.0f), 127.0f);
    unsigned int packed = (q0 & 0xff) | ((q1 & 0xff) << 8) |
                          ((q2 & 0xff) << 16) | ((q3 & 0xff) << 24);
    ((unsigned int*)dst)[idx] = packed;
  }
}

// ---------------------------------------------------------------------------
// i8 GEMM, REGISTER-DIRECT (no LDS staging, ZERO barriers in K-loop).
// Rationale (R3-R10 forensics): all barrier'd-staging schedules pinned at
// MfmaUtil ~15%; operands are L2-resident (gemm FETCH=12MB: qw=1MB hot
// everywhere, per-XCD A-slice ~2MB), and the 16x16x64 fragment = 16
// contiguous bytes at qx[row*1024 + kt*64 + q*16] — loadable directly.
// Line audit: one frag load = 16 distinct 64B lines/wave, same as a fully
// coalesced dwordx4 load; each line consumed by its 4 q-lanes (no overfetch).
// Block 256x128 (4 waves, 2Mx2N, wave 128x64), grid 512 = 2 blocks/CU;
// per K-tile per wave: 12 independent v4i loads + 32 MFMA. Latency hidden by
// 2 waves/SIMD + unroll-2 pipelining (no barriers to fence compiler motion).
// Est: MFMA 8.7us, L2 traffic ~390MB ~11us, stores 64MB ~10us, overlapped.
// Epilogue: per-wave-private LDS transpose + nontemporal v4f stores (R9).
// ---------------------------------------------------------------------------
#define NKT 16

__global__ __launch_bounds__(256, 2) void gemm_kernel(
    const signed char* __restrict__ qx, const signed char* __restrict__ qw,
    const float* __restrict__ amax, const float* __restrict__ bdeq,
    float* __restrict__ out) {
  __shared__ char lds[4 * 4352];  // per-wave 16x66 f32 transpose buffer

  const int tid  = threadIdx.x;
  const int w    = tid >> 6;
  const int lane = tid & 63;
  const int wm = w >> 1;   // 0..1 (128 rows)
  const int wn = w & 1;    // 0..1 (64 cols)
  const int fr = lane & 15;
  const int q  = lane >> 4;

  // XCD-aware swizzle (grid 512 = 8 XCDs x 64 contiguous) -> per-XCD A-slice ~2MB (L2-fits)
  const int bid = blockIdx.x;
  const int wg  = (bid & 7) * 64 + (bid >> 3);
  const int Mbase = (wg >> 3) * 256;
  const int Nbase = (wg & 7) * 128;

  // lane-fragment base pointers: row*K + q*16
  const signed char* pa = qx + (size_t)(Mbase + wm * 128 + fr) * K_DIM + q * 16;
  const signed char* pb = qw + (size_t)(Nbase + wn * 64 + fr) * K_DIM + q * 16;

  const float inv_denom = (amax[0] * amax[1]) * (1.0f / 16129.0f);

  v4i acc[8][4] = {};

#pragma unroll 2
  for (int kt = 0; kt < NKT; ++kt) {
    const int ko = kt * 64;
    v4i Ar[8], Br[4];
#pragma unroll
    for (int f = 0; f < 8; ++f)
      Ar[f] = *(const v4i*)(pa + (size_t)f * 16 * K_DIM + ko);
#pragma unroll
    for (int g = 0; g < 4; ++g)
      Br[g] = *(const v4i*)(pb + (size_t)g * 16 * K_DIM + ko);
#pragma unroll
    for (int f = 0; f < 8; ++f)
#pragma unroll
      for (int g = 0; g < 4; ++g)
        acc[f][g] = __builtin_amdgcn_mfma_i32_16x16x64_i8(Ar[f], Br[g], acc[f][g], 0, 0, 0);
  }

  // ---------------- epilogue: per-wave LDS transpose + nt stores ------------
  float bdq[4];
#pragma unroll
  for (int g = 0; g < 4; ++g) bdq[g] = bdeq[Nbase + wn * 64 + g * 16 + fr];

  float* lws = (float*)(lds + w * 4352);  // 16 x 66 f32, private per wave

  const int erow = lane >> 4;
  const int ecg  = lane & 15;
  float* const orow_base = out + (size_t)(Mbase + wm * 128) * N_OUT +
                           (Nbase + wn * 64) + ecg * 4;

#pragma unroll
  for (int f = 0; f < 8; ++f) {
    // scatter scaled acc into LDS: [row16 = q*4+i][col = g*16+fr]
#pragma unroll
    for (int g = 0; g < 4; ++g)
#pragma unroll
      for (int i = 0; i < 4; ++i)
        lws[(q * 4 + i) * 66 + g * 16 + fr] =
            (float)acc[f][g][i] * inv_denom + bdq[g];
    asm volatile("s_waitcnt lgkmcnt(0)" ::: "memory");  // wave-local ordering
    // gather row-major, store 256B-contiguous nontemporal v4f
#pragma unroll
    for (int t = 0; t < 4; ++t) {
      const int r16 = t * 4 + erow;
      v4f v = *(const v4f*)&lws[r16 * 66 + ecg * 4];
      __builtin_nontemporal_store(
          v, (v4f*)(orow_base + (size_t)(f * 16 + r16) * N_OUT));
    }
    asm volatile("s_waitcnt lgkmcnt(0)" ::: "memory");  // reads done before overwrite
  }
}

extern "C" void kernel_launch(void* const* d_in, const int* in_sizes, int n_in,
                              void* d_out, int out_size, void* d_ws, size_t ws_size,
                              hipStream_t stream) {
  const float* x = (const float*)d_in[0];
  const float* w = (const float*)d_in[1];
  const float* b = (const float*)d_in[2];
  float* out = (float*)d_out;

  char* ws = (char*)d_ws;
  float* amax = (float*)ws;                             // 3 floats
  float* bdeq = (float*)(ws + 256);                     // 4 KB
  float* px   = (float*)(ws + 8192);                    // 2048 partials
  float* pw   = (float*)(ws + 16384 + 8192);            // 256 partials
  signed char* qw = (signed char*)(ws + 65536);         // 1 MB
  signed char* qx = (signed char*)(ws + (1 << 21));     // 16 MB

  const int NPX = 2048, NPW = 256;
  hipLaunchKernelGGL(amax_both, dim3(NPX + NPW), dim3(256), 0, stream, x, w, px, pw);
  hipLaunchKernelGGL(finalize_kernel, dim3(1), dim3(256), 0, stream, px, NPX, pw, NPW, b, amax, bdeq);
  hipLaunchKernelGGL(quant_both, dim3(NPX + NPW), dim3(256), 0, stream, x, w, qx, qw, amax);
  hipLaunchKernelGGL(gemm_kernel, dim3(128 * 4), dim3(256), 0, stream, qx, qw, amax, bdeq, out);
}